// Round 3
// baseline (379.948 us; speedup 1.0000x reference)
//
#include <hip/hip_runtime.h>
#include <hip/hip_bf16.h>

// HardgroupAttention: B=4, N=1024, C=384, heads=12, hd=32, GP=20.
// qkv GEMM (SGPR-W) -> group argmax (fp64) -> attn_score2 (QK^T with SGPR-q,
// softmax+mask -> P~ bf16 + col partials) -> col_scale_v2 (V' = V/(colsum+eps))
// -> pv2 (out = P~ @ V', SGPR-V', swizzled LDS) -> proj GEMM.

#define B_    4
#define N_    1024
#define C_    384
#define H3_   1152
#define NH_   12
#define HD_   32
#define GP_   20
#define BH_   48
#define SCALE 0.17677669529663687f

// ---------------- GEMM NT with scalar-broadcast weights ---------------------
// C[M][Nn] = A[M][K] * W[Nn][K]^T. Block 64 rows x 64 cols; lane = row;
// wave ws owns cols ws*16..+15 (W rows read via wave-uniform scalar loads).
// A tile [64][32] in LDS, XOR-swizzled 16B chunks for conflict-free row reads.
__global__ __launch_bounds__(256) void gemm_nt_s(const float* __restrict__ A,
                                                 const float* __restrict__ Wt,
                                                 float* __restrict__ Cm,
                                                 int M, int Nn, int K) {
  __shared__ __align__(16) float a_s[64 * 32];
  int tid = threadIdx.x;
  int lane = tid & 63;
  int ws = __builtin_amdgcn_readfirstlane(tid >> 6);
  int bn = blockIdx.x, bm = blockIdx.y;
  const float* Ab = A + (size_t)(bm * 64) * K;
  const float* Wb = Wt + (size_t)(bn * 64 + ws * 16) * K;   // wave-uniform
  float acc[16] = {};
  for (int kk = 0; kk < K; kk += 32) {
    __syncthreads();
    #pragma unroll
    for (int t = 0; t < 2; ++t) {
      int f = tid * 8 + t * 4;
      int row = f >> 5, k4 = f & 31;
      float4 v = *(const float4*)(Ab + (size_t)row * K + kk + k4);
      *(float4*)&a_s[row * 32 + ((((k4 >> 2) ^ (row & 7)) & 7) << 2)] = v;
    }
    __syncthreads();
    float a[32];
    #pragma unroll
    for (int c = 0; c < 8; ++c)
      *(float4*)&a[c * 4] =
          *(const float4*)&a_s[lane * 32 + (((c ^ (lane & 7)) & 7) << 2)];
    #pragma unroll
    for (int ci = 0; ci < 16; ++ci) {
      const float* wr = Wb + (size_t)ci * K + kk;            // wave-uniform
      #pragma unroll
      for (int k = 0; k < 32; ++k) acc[ci] = fmaf(a[k], wr[k], acc[ci]);
    }
  }
  float* dst = Cm + (size_t)(bm * 64 + lane) * Nn + bn * 64 + ws * 16;
  #pragma unroll
  for (int q = 0; q < 4; ++q) {
    float4 v = {acc[q * 4], acc[q * 4 + 1], acc[q * 4 + 2], acc[q * 4 + 3]};
    *(float4*)(dst + q * 4) = v;
  }
}

// ---------------- group assignment (fp64 for argmax tie-safety) -------------
__global__ __launch_bounds__(320) void group_assign(const float* __restrict__ qkv,
                                                    const float* __restrict__ Wgp,
                                                    int* __restrict__ group) {
  __shared__ double sc[16][GP_];
  int tid = threadIdx.x;
  int r = tid / GP_, g = tid % GP_;
  int n = blockIdx.x * 16 + r;
  const float* row = qkv + (size_t)n * H3_;
  const float* w = Wgp + g * C_;
  double acc = 0.0;
  for (int c = 0; c < C_; ++c) acc += (double)row[c] * (double)w[c];
  sc[r][g] = acc;
  __syncthreads();
  if (g == 0) {
    int best = 0; double bv = sc[r][0];
    #pragma unroll
    for (int j = 1; j < GP_; ++j)
      if (sc[r][j] > bv) { bv = sc[r][j]; best = j; }
    group[n] = best;
  }
}

// ---------------- attn_score2: QK^T + softmax + mask -> P~ bf16 + colpart ---
// grid (32 qtiles, 48 bh); 256 thr = 4 waves; wave owns 8 rows (q via scalar
// loads); lane owns cols m = j*256 + jj*64 + lane (conflict-free k_s reads).
__global__ __launch_bounds__(256) void attn_score2(const float* __restrict__ qkv,
                                                   const int* __restrict__ group,
                                                   float* __restrict__ colpart,
                                                   __hip_bfloat16* __restrict__ pt) {
  __shared__ __align__(16) float k_s[256][36];
  __shared__ int g_s[1024];
  int tid = threadIdx.x;
  int lane = tid & 63;
  int ws = __builtin_amdgcn_readfirstlane(tid >> 6);
  int qtile = blockIdx.x, bh = blockIdx.y;
  int b = bh / NH_, hd = bh % NH_;
  const float* qbase = qkv + (size_t)b * N_ * H3_;
  int n0 = qtile * 32;
  const float* qrow = qbase + (size_t)(n0 + ws * 8) * H3_ + hd * HD_;  // uniform
  const int* grp = group + b * N_;

  *(int4*)&g_s[tid * 4] = *(const int4*)(grp + tid * 4);

  float S[4][8][4];
  #pragma unroll
  for (int j = 0; j < 4; ++j) {
    __syncthreads();
    #pragma unroll
    for (int p = 0; p < 8; ++p) {
      int m = p * 32 + (tid >> 3), d0 = (tid & 7) * 4;
      float4 v = *(const float4*)(qbase + (size_t)(j * 256 + m) * H3_ + C_ + hd * HD_ + d0);
      *(float4*)&k_s[m][d0] = v;
    }
    __syncthreads();
    #pragma unroll
    for (int i = 0; i < 8; ++i)
      #pragma unroll
      for (int jj = 0; jj < 4; ++jj) S[j][i][jj] = 0.f;
    #pragma unroll
    for (int d0 = 0; d0 < 32; d0 += 4) {
      float4 kv[4];
      #pragma unroll
      for (int jj = 0; jj < 4; ++jj) kv[jj] = *(const float4*)&k_s[jj * 64 + lane][d0];
      #pragma unroll
      for (int i = 0; i < 8; ++i) {
        float q0 = qrow[(size_t)i * H3_ + d0 + 0];   // wave-uniform -> SGPR
        float q1 = qrow[(size_t)i * H3_ + d0 + 1];
        float q2 = qrow[(size_t)i * H3_ + d0 + 2];
        float q3 = qrow[(size_t)i * H3_ + d0 + 3];
        #pragma unroll
        for (int jj = 0; jj < 4; ++jj) {
          S[j][i][jj] = fmaf(kv[jj].x, q0, S[j][i][jj]);
          S[j][i][jj] = fmaf(kv[jj].y, q1, S[j][i][jj]);
          S[j][i][jj] = fmaf(kv[jj].z, q2, S[j][i][jj]);
          S[j][i][jj] = fmaf(kv[jj].w, q3, S[j][i][jj]);
        }
      }
    }
  }

  // row stats (raw S; scale folded into exp arg)
  float mxs[8], rinv[8];
  #pragma unroll
  for (int i = 0; i < 8; ++i) {
    float m = S[0][i][0];
    #pragma unroll
    for (int j = 0; j < 4; ++j)
      #pragma unroll
      for (int jj = 0; jj < 4; ++jj) m = fmaxf(m, S[j][i][jj]);
    #pragma unroll
    for (int off = 1; off < 64; off <<= 1) m = fmaxf(m, __shfl_xor(m, off));
    mxs[i] = m * SCALE;
  }
  #pragma unroll
  for (int i = 0; i < 8; ++i) {
    float s = 0.f;
    #pragma unroll
    for (int j = 0; j < 4; ++j)
      #pragma unroll
      for (int jj = 0; jj < 4; ++jj) {
        float e = __expf(fmaf(S[j][i][jj], SCALE, -mxs[i]));
        S[j][i][jj] = e; s += e;
      }
    #pragma unroll
    for (int off = 1; off < 64; off <<= 1) s += __shfl_xor(s, off);
    rinv[i] = 1.0f / s;
  }

  bool samehead = (hd < NH_ / 2);
  int gr[8];
  #pragma unroll
  for (int i = 0; i < 8; ++i) gr[i] = grp[n0 + ws * 8 + i];   // uniform

  size_t pbB = ((size_t)bh * N_ + n0 + ws * 8) * (size_t)N_;
  float cp[4][4];
  #pragma unroll
  for (int j = 0; j < 4; ++j)
    #pragma unroll
    for (int jj = 0; jj < 4; ++jj) {
      int m = j * 256 + jj * 64 + lane;
      int gm = g_s[m];
      float c = 0.f;
      #pragma unroll
      for (int i = 0; i < 8; ++i) {
        bool keep = ((gm == gr[i]) == samehead);
        float p = keep ? S[j][i][jj] * rinv[i] : 0.f;
        c += p;
        pt[pbB + (size_t)i * N_ + m] = __float2bfloat16(p);
      }
      cp[j][jj] = c;
    }

  __syncthreads();                      // k_s reuse for colsum reduce
  float* cps = &k_s[0][0];
  #pragma unroll
  for (int j = 0; j < 4; ++j)
    #pragma unroll
    for (int jj = 0; jj < 4; ++jj)
      cps[ws * 1024 + j * 256 + jj * 64 + lane] = cp[j][jj];
  __syncthreads();
  int m4 = tid * 4;
  float4 a0 = *(float4*)&cps[0 + m4];
  float4 a1 = *(float4*)&cps[1024 + m4];
  float4 a2 = *(float4*)&cps[2048 + m4];
  float4 a3 = *(float4*)&cps[3072 + m4];
  float4 r = {a0.x + a1.x + a2.x + a3.x, a0.y + a1.y + a2.y + a3.y,
              a0.z + a1.z + a2.z + a3.z, a0.w + a1.w + a2.w + a3.w};
  *(float4*)(colpart + ((size_t)(bh * 32 + qtile)) * 1024 + m4) = r;
}

// ---------------- colsum (32 partials) + V' = V * 1/(colsum+eps) ------------
__global__ __launch_bounds__(256) void col_scale_v2(const float* __restrict__ colpart,
                                                    const float* __restrict__ qkv,
                                                    float* __restrict__ vprime) {
  int tid = threadIdx.x;
  int m = blockIdx.x * 256 + tid;
  int bh = blockIdx.y;
  int b = bh / NH_, hd = bh % NH_;
  const float* p = colpart + (size_t)bh * 32 * 1024 + m;
  float s = 0.f;
  #pragma unroll
  for (int t = 0; t < 32; ++t) s += p[t * 1024];
  float inv = 1.0f / (s + 1e-8f);
  const float* vsrc = qkv + ((size_t)b * N_ + m) * H3_ + 2 * C_ + hd * HD_;
  float* vdst = vprime + (size_t)bh * (N_ * HD_) + (size_t)m * HD_;
  #pragma unroll
  for (int d0 = 0; d0 < 32; d0 += 4) {
    float4 v = *(const float4*)(vsrc + d0);
    float4 o = {v.x * inv, v.y * inv, v.z * inv, v.w * inv};
    *(float4*)(vdst + d0) = o;
  }
}

// ---------------- pv2: out = P~(bf16) @ V' ----------------------------------
// grid (16 rowtiles, 48 bh); 256 thr = 4 waves; lane = row (64 rows/block),
// wave ws owns d-oct ws*8..+7 (V' via wave-uniform scalar loads).
// P~ tile [64][128] bf16 in LDS, XOR-swizzled (byte ^= (row&7)<<4).
__global__ __launch_bounds__(256) void pv2(const unsigned short* __restrict__ pt,
                                           const float* __restrict__ vprime,
                                           float* __restrict__ attnout) {
  __shared__ __align__(16) unsigned short p_s[64 * 128];   // 16 KB
  int tid = threadIdx.x;
  int lane = tid & 63;
  int ws = __builtin_amdgcn_readfirstlane(tid >> 6);
  int rt = blockIdx.x, bh = blockIdx.y;
  int b = bh / NH_, hd = bh % NH_;
  int r0 = rt * 64;
  const unsigned short* pbase = pt + ((size_t)bh * N_ + r0) * N_;
  const float* vbase = vprime + (size_t)bh * (N_ * HD_) + ws * 8;  // uniform
  float acc[8] = {};
  for (int mt = 0; mt < 8; ++mt) {
    __syncthreads();
    #pragma unroll
    for (int t = 0; t < 4; ++t) {
      int f = (t * 256 + tid) * 8;
      int row = f >> 7, mo = f & 127;
      uint4 v = *(const uint4*)(pbase + (size_t)row * N_ + mt * 128 + mo);
      *(uint4*)((char*)p_s + ((row * 256 + mo * 2) ^ ((row & 7) << 4))) = v;
    }
    __syncthreads();
    #pragma unroll
    for (int mc = 0; mc < 16; ++mc) {
      uint4 pk = *(const uint4*)((char*)p_s + ((lane * 256 + mc * 16) ^ ((lane & 7) << 4)));
      const float* vm = vbase + (size_t)(mt * 128 + mc * 8) * HD_;
      unsigned u[4] = {pk.x, pk.y, pk.z, pk.w};
      #pragma unroll
      for (int h = 0; h < 4; ++h) {
        float p0 = __uint_as_float(u[h] << 16);
        float p1 = __uint_as_float(u[h] & 0xffff0000u);
        const float* v0 = vm + (size_t)(2 * h) * HD_;      // wave-uniform
        const float* v1 = vm + (size_t)(2 * h + 1) * HD_;
        #pragma unroll
        for (int d = 0; d < 8; ++d) {
          acc[d] = fmaf(p0, v0[d], acc[d]);
          acc[d] = fmaf(p1, v1[d], acc[d]);
        }
      }
    }
  }
  float* dst = attnout + ((size_t)(b * N_ + r0 + lane)) * C_ + hd * HD_ + ws * 8;
  float4 o0 = {acc[0], acc[1], acc[2], acc[3]};
  float4 o1 = {acc[4], acc[5], acc[6], acc[7]};
  *(float4*)dst = o0;
  *(float4*)(dst + 4) = o1;
}

// ---------------- launch ----------------------------------------------------
extern "C" void kernel_launch(void* const* d_in, const int* in_sizes, int n_in,
                              void* d_out, int out_size, void* d_ws, size_t ws_size,
                              hipStream_t stream) {
  const float* x     = (const float*)d_in[0];
  const float* Wqkv  = (const float*)d_in[1];
  const float* Wproj = (const float*)d_in[2];
  const float* Wgp   = (const float*)d_in[3];
  float* out = (float*)d_out;
  float* ws  = (float*)d_ws;

  float* qkv     = ws;                         // 4,718,592 f
  float* attnout = ws + 4718592;               // 1,572,864 f
  float* colpart = ws + 6291456;               // 48*32*1024 = 1,572,864 f
  float* vprime  = ws + 7864320;               // 1,572,864 f
  int*   group   = (int*)(ws + 9437184);       // 4,096 i
  __hip_bfloat16* ptb = (__hip_bfloat16*)(ws + 9441280);   // 50,331,648 bf16
  unsigned short* ptu = (unsigned short*)ptb;

  gemm_nt_s<<<dim3(18, 64), 256, 0, stream>>>(x, Wqkv, qkv, 4096, H3_, C_);
  group_assign<<<dim3(256), 320, 0, stream>>>(qkv, Wgp, group);
  attn_score2<<<dim3(32, BH_), 256, 0, stream>>>(qkv, group, colpart, ptb);
  col_scale_v2<<<dim3(4, BH_), 256, 0, stream>>>(colpart, qkv, vprime);
  pv2<<<dim3(16, BH_), 256, 0, stream>>>(ptu, vprime, attnout);
  gemm_nt_s<<<dim3(6, 64), 256, 0, stream>>>(attnout, Wproj, out, 4096, C_, C_);
}

// Round 4
// 262.747 us; speedup vs baseline: 1.4461x; 1.4461x over previous
//
#include <hip/hip_runtime.h>
#include <hip/hip_bf16.h>

// HardgroupAttention: B=4, N=1024, C=384, heads=12, hd=32, GP=20.
// qkv GEMM (fp32, exact for argmax) -> group argmax (fp64) ->
// prep (bf16 hi/lo split of Q,K; V transposed bf16 hi/lo) ->
// pass1 MFMA (rowmax, rowsum, colsum partial sweeps) -> col_inv ->
// pass2 MFMA (recompute S, p~ = exp*rinv*colinv*mask, LDS transpose, PV) ->
// proj GEMM. MFMA: 16x16x32 bf16, K=32=head_dim (one mfma per tile).

#define B_    4
#define N_    1024
#define C_    384
#define H3_   1152
#define NH_   12
#define HD_   32
#define GP_   20
#define BH_   48
#define SCALE 0.17677669529663687f

typedef __attribute__((ext_vector_type(8))) short bf16x8;
typedef __attribute__((ext_vector_type(4))) float f32x4;

static __device__ __forceinline__ unsigned short f2bf(float x) {
  union { float f; unsigned u; } v; v.f = x;
  unsigned r = v.u + 0x7fff + ((v.u >> 16) & 1);   // RNE
  return (unsigned short)(r >> 16);
}
static __device__ __forceinline__ float bf2f(unsigned short h) {
  union { unsigned u; float f; } v; v.u = ((unsigned)h) << 16;
  return v.f;
}

// ---------------- fp32 NT GEMM (round-2 version, exact path) ----------------
__global__ __launch_bounds__(256) void gemm_nt(const float* __restrict__ A,
                                               const float* __restrict__ Bm,
                                               float* __restrict__ Cm,
                                               int M, int Nn, int K) {
  __shared__ float a_s[32][68];
  __shared__ float b_s[32][68];
  int tid = threadIdx.x;
  int tm = tid >> 4, tn = tid & 15;
  int bm = blockIdx.y, bn = blockIdx.x;
  const float* Ab = A + (size_t)bm * 64 * K;
  const float* Bb = Bm + (size_t)bn * 64 * K;
  float acc[4][4] = {};
  for (int kk = 0; kk < K; kk += 32) {
    #pragma unroll
    for (int l = 0; l < 2; ++l) {
      int idx = tid + l * 256;
      int row = idx >> 3;
      int k4  = (idx & 7) * 4;
      float4 av = *(const float4*)(Ab + (size_t)row * K + kk + k4);
      float4 bv = *(const float4*)(Bb + (size_t)row * K + kk + k4);
      a_s[k4 + 0][row] = av.x; a_s[k4 + 1][row] = av.y;
      a_s[k4 + 2][row] = av.z; a_s[k4 + 3][row] = av.w;
      b_s[k4 + 0][row] = bv.x; b_s[k4 + 1][row] = bv.y;
      b_s[k4 + 2][row] = bv.z; b_s[k4 + 3][row] = bv.w;
    }
    __syncthreads();
    #pragma unroll
    for (int k = 0; k < 32; ++k) {
      float4 av = *(const float4*)&a_s[k][tm * 4];
      float4 bv = *(const float4*)&b_s[k][tn * 4];
      float aa[4] = {av.x, av.y, av.z, av.w};
      float bb[4] = {bv.x, bv.y, bv.z, bv.w};
      #pragma unroll
      for (int i = 0; i < 4; ++i)
        #pragma unroll
        for (int j = 0; j < 4; ++j)
          acc[i][j] = fmaf(aa[i], bb[j], acc[i][j]);
    }
    __syncthreads();
  }
  int r0 = bm * 64 + tm * 4, c0 = bn * 64 + tn * 4;
  #pragma unroll
  for (int i = 0; i < 4; ++i) {
    float4 v = {acc[i][0], acc[i][1], acc[i][2], acc[i][3]};
    *(float4*)(Cm + (size_t)(r0 + i) * Nn + c0) = v;
  }
}

// ---------------- group assignment (fp64, argmax tie-safety) ----------------
__global__ __launch_bounds__(320) void group_assign(const float* __restrict__ qkv,
                                                    const float* __restrict__ Wgp,
                                                    int* __restrict__ group) {
  __shared__ double sc[16][GP_];
  int tid = threadIdx.x;
  int r = tid / GP_, g = tid % GP_;
  int n = blockIdx.x * 16 + r;
  const float* row = qkv + (size_t)n * H3_;
  const float* w = Wgp + g * C_;
  double acc = 0.0;
  for (int c = 0; c < C_; ++c) acc += (double)row[c] * (double)w[c];
  sc[r][g] = acc;
  __syncthreads();
  if (g == 0) {
    int best = 0; double bv = sc[r][0];
    #pragma unroll
    for (int j = 1; j < GP_; ++j)
      if (sc[r][j] > bv) { bv = sc[r][j]; best = j; }
    group[n] = best;
  }
}

// ---------------- prep: qkv fp32 -> bf16 hi/lo buffers ----------------------
// Qh/Ql/Kh/Kl: [bh][n][32] ushort. Vth/Vtl: [bh][d=32][n=1024] ushort.
__global__ __launch_bounds__(256) void prep(const float* __restrict__ qkv,
                                            unsigned short* __restrict__ Qh,
                                            unsigned short* __restrict__ Ql,
                                            unsigned short* __restrict__ Kh,
                                            unsigned short* __restrict__ Kl,
                                            unsigned short* __restrict__ Vth,
                                            unsigned short* __restrict__ Vtl) {
  __shared__ unsigned short vh_s[32][36];
  __shared__ unsigned short vl_s[32][36];
  int tid = threadIdx.x;
  int row = tid >> 3, d4 = (tid & 7) * 4;
  int bh = blockIdx.y, b = bh / NH_, hd = bh % NH_;
  int n = blockIdx.x * 32 + row;
  const float* base = qkv + ((size_t)b * N_ + n) * H3_ + hd * HD_ + d4;
  float4 q = *(const float4*)(base);
  float4 k = *(const float4*)(base + C_);
  float4 v = *(const float4*)(base + 2 * C_);
  float qa[4] = {q.x, q.y, q.z, q.w};
  float ka[4] = {k.x, k.y, k.z, k.w};
  float va[4] = {v.x, v.y, v.z, v.w};
  unsigned short qh[4], ql[4], kh[4], kl[4];
  #pragma unroll
  for (int i = 0; i < 4; ++i) {
    qh[i] = f2bf(qa[i]); ql[i] = f2bf(qa[i] - bf2f(qh[i]));
    kh[i] = f2bf(ka[i]); kl[i] = f2bf(ka[i] - bf2f(kh[i]));
    unsigned short vh = f2bf(va[i]);
    vh_s[d4 + i][row] = vh;
    vl_s[d4 + i][row] = f2bf(va[i] - bf2f(vh));
  }
  size_t o = ((size_t)bh * N_ + n) * HD_ + d4;
  uint2 pq = {(unsigned)qh[0] | ((unsigned)qh[1] << 16),
              (unsigned)qh[2] | ((unsigned)qh[3] << 16)};
  uint2 pql = {(unsigned)ql[0] | ((unsigned)ql[1] << 16),
               (unsigned)ql[2] | ((unsigned)ql[3] << 16)};
  uint2 pk = {(unsigned)kh[0] | ((unsigned)kh[1] << 16),
              (unsigned)kh[2] | ((unsigned)kh[3] << 16)};
  uint2 pkl = {(unsigned)kl[0] | ((unsigned)kl[1] << 16),
               (unsigned)kl[2] | ((unsigned)kl[3] << 16)};
  *(uint2*)(Qh + o) = pq;  *(uint2*)(Ql + o) = pql;
  *(uint2*)(Kh + o) = pk;  *(uint2*)(Kl + o) = pkl;
  __syncthreads();
  int d = tid >> 3, c4 = (tid & 7) * 4;
  int kv0 = blockIdx.x * 32;
  unsigned short h0 = vh_s[d][c4], h1 = vh_s[d][c4 + 1],
                 h2 = vh_s[d][c4 + 2], h3 = vh_s[d][c4 + 3];
  unsigned short l0 = vl_s[d][c4], l1 = vl_s[d][c4 + 1],
                 l2 = vl_s[d][c4 + 2], l3 = vl_s[d][c4 + 3];
  uint2 pv = {(unsigned)h0 | ((unsigned)h1 << 16),
              (unsigned)h2 | ((unsigned)h3 << 16)};
  uint2 pvl = {(unsigned)l0 | ((unsigned)l1 << 16),
               (unsigned)l2 | ((unsigned)l3 << 16)};
  size_t ov = ((size_t)bh * HD_ + d) * N_ + kv0 + c4;
  *(uint2*)(Vth + ov) = pv;
  *(uint2*)(Vtl + ov) = pvl;
}

// ---------------- pass1: rowmax / rowsum / colsum-partial sweeps ------------
// grid (16 qblocks of 64 rows, 48 bh); 256 thr = 4 waves; wave = 16 rows.
// mfma model: D[r][c] = sum_k A[r][k]*B[c][k]; A lane: r=l&15,k=(l>>4)*8+j;
// B lane: c=l&15,k same; D lane: r=(l>>4)*4+t, c=l&15.  [guide §3, m89]
__global__ __launch_bounds__(256) void attn_pass1m(const unsigned short* __restrict__ Qh,
                                                   const unsigned short* __restrict__ Ql,
                                                   const unsigned short* __restrict__ Kh,
                                                   const unsigned short* __restrict__ Kl,
                                                   const int* __restrict__ group,
                                                   float* __restrict__ row_stats,
                                                   float* __restrict__ colpart) {
  __shared__ int g_s[1024];
  __shared__ float colpart_s[4][1024];
  int tid = threadIdx.x;
  int l = tid & 63, w = tid >> 6;
  int lanelo = l & 15, g16 = l >> 4;
  int blk = blockIdx.x, bh = blockIdx.y;
  int b = bh / NH_;
  bool samehead = ((bh % NH_) < NH_ / 2);
  int q0 = blk * 64 + w * 16;

  *(int4*)&g_s[tid * 4] = *(const int4*)(group + b * N_ + tid * 4);

  size_t bhb = (size_t)bh * (N_ * HD_);
  bf16x8 aQh = *(const bf16x8*)(Qh + bhb + (size_t)(q0 + lanelo) * HD_ + g16 * 8);
  bf16x8 aQl = *(const bf16x8*)(Ql + bhb + (size_t)(q0 + lanelo) * HD_ + g16 * 8);
  const unsigned short* khb = Kh + bhb + g16 * 8;
  const unsigned short* klb = Kl + bhb + g16 * 8;
  __syncthreads();
  int gq[4];
  #pragma unroll
  for (int t = 0; t < 4; ++t) gq[t] = g_s[q0 + g16 * 4 + t];

  // sweep A: row max
  float m4[4] = {-3e38f, -3e38f, -3e38f, -3e38f};
  #pragma unroll 4
  for (int kt = 0; kt < 64; ++kt) {
    bf16x8 bh8 = *(const bf16x8*)(khb + (size_t)(kt * 16 + lanelo) * HD_);
    bf16x8 bl8 = *(const bf16x8*)(klb + (size_t)(kt * 16 + lanelo) * HD_);
    f32x4 acc = {0.f, 0.f, 0.f, 0.f};
    acc = __builtin_amdgcn_mfma_f32_16x16x32_bf16(aQh, bh8, acc, 0, 0, 0);
    acc = __builtin_amdgcn_mfma_f32_16x16x32_bf16(aQh, bl8, acc, 0, 0, 0);
    acc = __builtin_amdgcn_mfma_f32_16x16x32_bf16(aQl, bh8, acc, 0, 0, 0);
    #pragma unroll
    for (int t = 0; t < 4; ++t) m4[t] = fmaxf(m4[t], acc[t]);
  }
  #pragma unroll
  for (int t = 0; t < 4; ++t) {
    #pragma unroll
    for (int off = 1; off < 16; off <<= 1)
      m4[t] = fmaxf(m4[t], __shfl_xor(m4[t], off));
    m4[t] *= SCALE;                         // msc
  }

  // sweep B: row sum
  float s4[4] = {0.f, 0.f, 0.f, 0.f};
  #pragma unroll 4
  for (int kt = 0; kt < 64; ++kt) {
    bf16x8 bh8 = *(const bf16x8*)(khb + (size_t)(kt * 16 + lanelo) * HD_);
    bf16x8 bl8 = *(const bf16x8*)(klb + (size_t)(kt * 16 + lanelo) * HD_);
    f32x4 acc = {0.f, 0.f, 0.f, 0.f};
    acc = __builtin_amdgcn_mfma_f32_16x16x32_bf16(aQh, bh8, acc, 0, 0, 0);
    acc = __builtin_amdgcn_mfma_f32_16x16x32_bf16(aQh, bl8, acc, 0, 0, 0);
    acc = __builtin_amdgcn_mfma_f32_16x16x32_bf16(aQl, bh8, acc, 0, 0, 0);
    #pragma unroll
    for (int t = 0; t < 4; ++t)
      s4[t] += __expf(fmaf(acc[t], SCALE, -m4[t]));
  }
  #pragma unroll
  for (int t = 0; t < 4; ++t) {
    #pragma unroll
    for (int off = 1; off < 16; off <<= 1) s4[t] += __shfl_xor(s4[t], off);
    s4[t] = 1.0f / s4[t];                   // rinv
  }
  if (lanelo == 0) {
    #pragma unroll
    for (int t = 0; t < 4; ++t) {
      float2 rs = {m4[t], s4[t]};
      *(float2*)(row_stats + ((size_t)bh * N_ + q0 + g16 * 4 + t) * 2) = rs;
    }
  }

  // sweep C: masked col partial sums
  #pragma unroll 2
  for (int kt = 0; kt < 64; ++kt) {
    bf16x8 bh8 = *(const bf16x8*)(khb + (size_t)(kt * 16 + lanelo) * HD_);
    bf16x8 bl8 = *(const bf16x8*)(klb + (size_t)(kt * 16 + lanelo) * HD_);
    f32x4 acc = {0.f, 0.f, 0.f, 0.f};
    acc = __builtin_amdgcn_mfma_f32_16x16x32_bf16(aQh, bh8, acc, 0, 0, 0);
    acc = __builtin_amdgcn_mfma_f32_16x16x32_bf16(aQh, bl8, acc, 0, 0, 0);
    acc = __builtin_amdgcn_mfma_f32_16x16x32_bf16(aQl, bh8, acc, 0, 0, 0);
    int gcol = g_s[kt * 16 + lanelo];
    float cs = 0.f;
    #pragma unroll
    for (int t = 0; t < 4; ++t) {
      bool keep = ((gcol == gq[t]) == samehead);
      float p = __expf(fmaf(acc[t], SCALE, -m4[t])) * s4[t];
      cs += keep ? p : 0.f;
    }
    cs += __shfl_xor(cs, 16);
    cs += __shfl_xor(cs, 32);
    if (l < 16) colpart_s[w][kt * 16 + l] = cs;
  }
  __syncthreads();
  int c0 = tid * 4;
  float4 p0 = *(float4*)&colpart_s[0][c0];
  float4 p1 = *(float4*)&colpart_s[1][c0];
  float4 p2 = *(float4*)&colpart_s[2][c0];
  float4 p3 = *(float4*)&colpart_s[3][c0];
  float4 r = {p0.x + p1.x + p2.x + p3.x, p0.y + p1.y + p2.y + p3.y,
              p0.z + p1.z + p2.z + p3.z, p0.w + p1.w + p2.w + p3.w};
  *(float4*)(colpart + ((size_t)bh * 16 + blk) * 1024 + c0) = r;
}

// ---------------- col_inv: 1/(sum over 16 qblock partials + eps) ------------
__global__ __launch_bounds__(256) void col_inv(const float* __restrict__ colpart,
                                               float* __restrict__ colinv) {
  int tid = threadIdx.x;
  int m = blockIdx.x * 256 + tid;
  int bh = blockIdx.y;
  const float* p = colpart + (size_t)bh * 16 * 1024 + m;
  float s = 0.f;
  #pragma unroll
  for (int t = 0; t < 16; ++t) s += p[t * 1024];
  colinv[(size_t)bh * N_ + m] = 1.0f / (s + 1e-8f);
}

// ---------------- pass2: recompute S, p~, LDS transpose, PV MFMA ------------
__global__ __launch_bounds__(256) void attn_pass2m(const unsigned short* __restrict__ Qh,
                                                   const unsigned short* __restrict__ Ql,
                                                   const unsigned short* __restrict__ Kh,
                                                   const unsigned short* __restrict__ Kl,
                                                   const unsigned short* __restrict__ Vth,
                                                   const unsigned short* __restrict__ Vtl,
                                                   const int* __restrict__ group,
                                                   const float* __restrict__ row_stats,
                                                   const float* __restrict__ colinv,
                                                   float* __restrict__ attnout) {
  __shared__ int g_s[1024];
  __shared__ float ci_s[1024];
  __shared__ float p_lds[4][16][36];
  int tid = threadIdx.x;
  int l = tid & 63, w = tid >> 6;
  int lanelo = l & 15, g16 = l >> 4;
  int blk = blockIdx.x, bh = blockIdx.y;
  int b = bh / NH_, hd = bh % NH_;
  bool samehead = (hd < NH_ / 2);
  int q0 = blk * 64 + w * 16;

  *(int4*)&g_s[tid * 4] = *(const int4*)(group + b * N_ + tid * 4);
  *(float4*)&ci_s[tid * 4] = *(const float4*)(colinv + (size_t)bh * N_ + tid * 4);

  size_t bhb = (size_t)bh * (N_ * HD_);
  bf16x8 aQh = *(const bf16x8*)(Qh + bhb + (size_t)(q0 + lanelo) * HD_ + g16 * 8);
  bf16x8 aQl = *(const bf16x8*)(Ql + bhb + (size_t)(q0 + lanelo) * HD_ + g16 * 8);
  const unsigned short* khb = Kh + bhb + g16 * 8;
  const unsigned short* klb = Kl + bhb + g16 * 8;
  float msc[4], rinv[4];
  #pragma unroll
  for (int t = 0; t < 4; ++t) {
    float2 rs = *(const float2*)(row_stats + ((size_t)bh * N_ + q0 + g16 * 4 + t) * 2);
    msc[t] = rs.x; rinv[t] = rs.y;
  }
  __syncthreads();
  int gq[4];
  #pragma unroll
  for (int t = 0; t < 4; ++t) gq[t] = g_s[q0 + g16 * 4 + t];

  f32x4 o0 = {0.f, 0.f, 0.f, 0.f};
  f32x4 o1 = {0.f, 0.f, 0.f, 0.f};
  const unsigned short* vhb = Vth + bhb + g16 * 8;
  const unsigned short* vlb = Vtl + bhb + g16 * 8;

  for (int ch = 0; ch < 32; ++ch) {
    #pragma unroll
    for (int kt2 = 0; kt2 < 2; ++kt2) {
      int kvt = ch * 2 + kt2;
      bf16x8 bh8 = *(const bf16x8*)(khb + (size_t)(kvt * 16 + lanelo) * HD_);
      bf16x8 bl8 = *(const bf16x8*)(klb + (size_t)(kvt * 16 + lanelo) * HD_);
      f32x4 acc = {0.f, 0.f, 0.f, 0.f};
      acc = __builtin_amdgcn_mfma_f32_16x16x32_bf16(aQh, bh8, acc, 0, 0, 0);
      acc = __builtin_amdgcn_mfma_f32_16x16x32_bf16(aQh, bl8, acc, 0, 0, 0);
      acc = __builtin_amdgcn_mfma_f32_16x16x32_bf16(aQl, bh8, acc, 0, 0, 0);
      int kvcol = kvt * 16 + lanelo;
      int gcol = g_s[kvcol];
      float ci = ci_s[kvcol];
      #pragma unroll
      for (int t = 0; t < 4; ++t) {
        bool keep = ((gcol == gq[t]) == samehead);
        float p = __expf(fmaf(acc[t], SCALE, -msc[t])) * rinv[t] * ci;
        p_lds[w][g16 * 4 + t][kt2 * 16 + lanelo] = keep ? p : 0.f;
      }
    }
    // transpose read: lane -> A-frag of P~ (rows q=l&15, kv-slice g16*8..+7)
    float pf[8];
    *(float4*)&pf[0] = *(float4*)&p_lds[w][lanelo][g16 * 8];
    *(float4*)&pf[4] = *(float4*)&p_lds[w][lanelo][g16 * 8 + 4];
    bf16x8 pa;
    #pragma unroll
    for (int j = 0; j < 8; ++j) pa[j] = (short)f2bf(pf[j]);
    // V frags + PV MFMA (d tiles 0,1; V split hi+lo)
    size_t vo0 = (size_t)lanelo * N_ + ch * 32;
    size_t vo1 = (size_t)(16 + lanelo) * N_ + ch * 32;
    bf16x8 v0h = *(const bf16x8*)(vhb + vo0);
    bf16x8 v0l = *(const bf16x8*)(vlb + vo0);
    bf16x8 v1h = *(const bf16x8*)(vhb + vo1);
    bf16x8 v1l = *(const bf16x8*)(vlb + vo1);
    o0 = __builtin_amdgcn_mfma_f32_16x16x32_bf16(pa, v0h, o0, 0, 0, 0);
    o0 = __builtin_amdgcn_mfma_f32_16x16x32_bf16(pa, v0l, o0, 0, 0, 0);
    o1 = __builtin_amdgcn_mfma_f32_16x16x32_bf16(pa, v1h, o1, 0, 0, 0);
    o1 = __builtin_amdgcn_mfma_f32_16x16x32_bf16(pa, v1l, o1, 0, 0, 0);
  }
  #pragma unroll
  for (int t = 0; t < 4; ++t) {
    size_t rb = ((size_t)(b * N_ + q0 + g16 * 4 + t)) * C_ + hd * HD_;
    attnout[rb + lanelo]      = o0[t];
    attnout[rb + 16 + lanelo] = o1[t];
  }
}

// ---------------- launch ----------------------------------------------------
extern "C" void kernel_launch(void* const* d_in, const int* in_sizes, int n_in,
                              void* d_out, int out_size, void* d_ws, size_t ws_size,
                              hipStream_t stream) {
  const float* x     = (const float*)d_in[0];
  const float* Wqkv  = (const float*)d_in[1];
  const float* Wproj = (const float*)d_in[2];
  const float* Wgp   = (const float*)d_in[3];
  float* out = (float*)d_out;
  float* ws  = (float*)d_ws;

  float* qkv       = ws;                       // 4,718,592 f
  float* attnout   = ws + 4718592;             // 1,572,864 f
  float* colpart   = ws + 6291456;             // 48*16*1024 = 786,432 f
  float* row_stats = ws + 7077888;             // 48*1024*2  =  98,304 f
  float* colinv    = ws + 7176192;             // 49,152 f
  int*   group     = (int*)(ws + 7225344);     // 4,096 i
  unsigned short* bfb = (unsigned short*)(ws + 7229440);
  const size_t BSZ = (size_t)BH_ * N_ * HD_;   // 1,572,864 ushorts each
  unsigned short* Qh  = bfb;
  unsigned short* Ql  = bfb + BSZ;
  unsigned short* Kh  = bfb + 2 * BSZ;
  unsigned short* Kl  = bfb + 3 * BSZ;
  unsigned short* Vth = bfb + 4 * BSZ;
  unsigned short* Vtl = bfb + 5 * BSZ;         // ends ~48 MB into ws

  gemm_nt<<<dim3(18, 64), 256, 0, stream>>>(x, Wqkv, qkv, 4096, H3_, C_);
  group_assign<<<dim3(256), 320, 0, stream>>>(qkv, Wgp, group);
  prep<<<dim3(32, BH_), 256, 0, stream>>>(qkv, Qh, Ql, Kh, Kl, Vth, Vtl);
  attn_pass1m<<<dim3(16, BH_), 256, 0, stream>>>(Qh, Ql, Kh, Kl, group,
                                                 row_stats, colpart);
  col_inv<<<dim3(4, BH_), 256, 0, stream>>>(colpart, colinv);
  attn_pass2m<<<dim3(16, BH_), 256, 0, stream>>>(Qh, Ql, Kh, Kl, Vth, Vtl,
                                                 group, row_stats, colinv, attnout);
  gemm_nt<<<dim3(6, 64), 256, 0, stream>>>(attnout, Wproj, out, 4096, C_, C_);
}

// Round 5
// 227.163 us; speedup vs baseline: 1.6726x; 1.1566x over previous
//
#include <hip/hip_runtime.h>
#include <hip/hip_bf16.h>

// HardgroupAttention: B=4, N=1024, C=384, heads=12, hd=32, GP=20.
// qkv GEMM fp32 -> wgp_fuse (M = Wgp@Wq, fp64) -> group argmax (fp64 from x)
// -> prep2 (bf16 hi/lo of scaled-Q, K) -> score (1 MFMA QK^T sweep, no-max
// softmax, mask -> P' bf16 [bh][mt][n][16] + rinv) -> colpass (colsum =
// sum_n P'*rinv, colinv -> V' = V*colinv bf16 hi/lo transposed) ->
// pv (O = P' @ V' MFMA, epilogue *rinv) -> proj GEMM.

#define B_    4
#define N_    1024
#define C_    384
#define H3_   1152
#define NH_   12
#define HD_   32
#define GP_   20
#define BH_   48
#define SCALE 0.17677669529663687f

typedef __attribute__((ext_vector_type(8))) short bf16x8;
typedef __attribute__((ext_vector_type(4))) float f32x4;

static __device__ __forceinline__ unsigned short f2bf(float x) {
  union { float f; unsigned u; } v; v.f = x;
  unsigned r = v.u + 0x7fff + ((v.u >> 16) & 1);   // RNE
  return (unsigned short)(r >> 16);
}
static __device__ __forceinline__ float bf2f(unsigned short h) {
  union { unsigned u; float f; } v; v.u = ((unsigned)h) << 16;
  return v.f;
}

// ---------------- fp32 NT GEMM (exact; qkv + proj) --------------------------
__global__ __launch_bounds__(256) void gemm_nt(const float* __restrict__ A,
                                               const float* __restrict__ Bm,
                                               float* __restrict__ Cm,
                                               int M, int Nn, int K) {
  __shared__ float a_s[32][68];
  __shared__ float b_s[32][68];
  int tid = threadIdx.x;
  int tm = tid >> 4, tn = tid & 15;
  int bm = blockIdx.y, bn = blockIdx.x;
  const float* Ab = A + (size_t)bm * 64 * K;
  const float* Bb = Bm + (size_t)bn * 64 * K;
  float acc[4][4] = {};
  for (int kk = 0; kk < K; kk += 32) {
    #pragma unroll
    for (int l = 0; l < 2; ++l) {
      int idx = tid + l * 256;
      int row = idx >> 3;
      int k4  = (idx & 7) * 4;
      float4 av = *(const float4*)(Ab + (size_t)row * K + kk + k4);
      float4 bv = *(const float4*)(Bb + (size_t)row * K + kk + k4);
      a_s[k4 + 0][row] = av.x; a_s[k4 + 1][row] = av.y;
      a_s[k4 + 2][row] = av.z; a_s[k4 + 3][row] = av.w;
      b_s[k4 + 0][row] = bv.x; b_s[k4 + 1][row] = bv.y;
      b_s[k4 + 2][row] = bv.z; b_s[k4 + 3][row] = bv.w;
    }
    __syncthreads();
    #pragma unroll
    for (int k = 0; k < 32; ++k) {
      float4 av = *(const float4*)&a_s[k][tm * 4];
      float4 bv = *(const float4*)&b_s[k][tn * 4];
      float aa[4] = {av.x, av.y, av.z, av.w};
      float bb[4] = {bv.x, bv.y, bv.z, bv.w};
      #pragma unroll
      for (int i = 0; i < 4; ++i)
        #pragma unroll
        for (int j = 0; j < 4; ++j)
          acc[i][j] = fmaf(aa[i], bb[j], acc[i][j]);
    }
    __syncthreads();
  }
  int r0 = bm * 64 + tm * 4, c0 = bn * 64 + tn * 4;
  #pragma unroll
  for (int i = 0; i < 4; ++i) {
    float4 v = {acc[i][0], acc[i][1], acc[i][2], acc[i][3]};
    *(float4*)(Cm + (size_t)(r0 + i) * Nn + c0) = v;
  }
}

// ---------------- M[g][c] = sum_j Wgp[g][j] * Wqkv[j][c]  (fp64) ------------
__global__ __launch_bounds__(256) void wgp_fuse(const float* __restrict__ Wqkv,
                                                const float* __restrict__ Wgp,
                                                double* __restrict__ M) {
  int idx = blockIdx.x * 256 + threadIdx.x;
  if (idx >= GP_ * C_) return;
  int g = idx / C_, c = idx % C_;
  double acc = 0.0;
  for (int j = 0; j < C_; ++j)
    acc += (double)Wgp[g * C_ + j] * (double)Wqkv[(size_t)j * C_ + c];
  M[idx] = acc;
}

// ---------------- group argmax from exact x (fp64) --------------------------
__global__ __launch_bounds__(320) void group_assign2(const float* __restrict__ x,
                                                     const double* __restrict__ M,
                                                     int* __restrict__ group) {
  __shared__ double sc[16][GP_];
  int tid = threadIdx.x;
  int r = tid / GP_, g = tid % GP_;
  int n = blockIdx.x * 16 + r;
  const float* row = x + (size_t)n * C_;
  const double* w = M + (size_t)g * C_;
  double acc = 0.0;
  for (int c = 0; c < C_; ++c) acc += (double)row[c] * w[c];
  sc[r][g] = acc;
  __syncthreads();
  if (g == 0) {
    int best = 0; double bv = sc[r][0];
    #pragma unroll
    for (int j = 1; j < GP_; ++j)
      if (sc[r][j] > bv) { bv = sc[r][j]; best = j; }
    group[n] = best;
  }
}

// ---------------- prep2: qkv fp32 -> bf16 hi/lo (Q pre-scaled) --------------
__global__ __launch_bounds__(256) void prep2(const float* __restrict__ qkv,
                                             unsigned short* __restrict__ Qh,
                                             unsigned short* __restrict__ Ql,
                                             unsigned short* __restrict__ Kh,
                                             unsigned short* __restrict__ Kl) {
  int tid = threadIdx.x;
  int row = tid >> 3, d4 = (tid & 7) * 4;
  int bh = blockIdx.y, b = bh / NH_, hd = bh % NH_;
  int n = blockIdx.x * 32 + row;
  const float* base = qkv + ((size_t)b * N_ + n) * H3_ + hd * HD_ + d4;
  float4 q = *(const float4*)(base);
  float4 k = *(const float4*)(base + C_);
  float qa[4] = {q.x * SCALE, q.y * SCALE, q.z * SCALE, q.w * SCALE};
  float ka[4] = {k.x, k.y, k.z, k.w};
  unsigned short qh[4], ql[4], kh[4], kl[4];
  #pragma unroll
  for (int i = 0; i < 4; ++i) {
    qh[i] = f2bf(qa[i]); ql[i] = f2bf(qa[i] - bf2f(qh[i]));
    kh[i] = f2bf(ka[i]); kl[i] = f2bf(ka[i] - bf2f(kh[i]));
  }
  size_t o = ((size_t)bh * N_ + n) * HD_ + d4;
  uint2 pq  = {(unsigned)qh[0] | ((unsigned)qh[1] << 16),
               (unsigned)qh[2] | ((unsigned)qh[3] << 16)};
  uint2 pql = {(unsigned)ql[0] | ((unsigned)ql[1] << 16),
               (unsigned)ql[2] | ((unsigned)ql[3] << 16)};
  uint2 pk  = {(unsigned)kh[0] | ((unsigned)kh[1] << 16),
               (unsigned)kh[2] | ((unsigned)kh[3] << 16)};
  uint2 pkl = {(unsigned)kl[0] | ((unsigned)kl[1] << 16),
               (unsigned)kl[2] | ((unsigned)kl[3] << 16)};
  *(uint2*)(Qh + o) = pq;  *(uint2*)(Ql + o) = pql;
  *(uint2*)(Kh + o) = pk;  *(uint2*)(Kl + o) = pkl;
}

// ---------------- score: single QK^T sweep -> P' bf16 + rinv ----------------
// grid (16,48) XCD-swizzled; 4 waves, wave = 16 q-rows. K staged in LDS
// (XOR-swizzled 16B chunks). No rowmax (exp bounded). P' = mask * exp.
__global__ __launch_bounds__(256) void score(const unsigned short* __restrict__ Qh,
                                             const unsigned short* __restrict__ Ql,
                                             const unsigned short* __restrict__ Kh,
                                             const unsigned short* __restrict__ Kl,
                                             const int* __restrict__ group,
                                             float* __restrict__ rinv,
                                             unsigned short* __restrict__ Pp) {
  __shared__ __align__(16) unsigned short kbufh[4096];   // 128 kv x 32 d, swz
  __shared__ __align__(16) unsigned short kbufl[4096];
  __shared__ __align__(16) float bounce[4][256];         // per-wave 16x16, swz
  __shared__ int g_s[1024];
  int tid = threadIdx.x;
  int l = tid & 63, w = tid >> 6;
  int lanelo = l & 15, g16 = l >> 4;
  int flat = blockIdx.y * 16 + blockIdx.x;
  int nf = (flat & 7) * 96 + (flat >> 3);                // bijective XCD swz
  int bh = nf >> 4, blk = nf & 15;
  int b = bh / NH_;
  bool samehead = ((bh % NH_) < NH_ / 2);
  int q0 = blk * 64 + w * 16;
  size_t bhb = (size_t)bh * (N_ * HD_);

  *(int4*)&g_s[tid * 4] = *(const int4*)(group + b * N_ + tid * 4);
  bf16x8 aQh = *(const bf16x8*)(Qh + bhb + (size_t)(q0 + lanelo) * HD_ + g16 * 8);
  bf16x8 aQl = *(const bf16x8*)(Ql + bhb + (size_t)(q0 + lanelo) * HD_ + g16 * 8);
  __syncthreads();
  int gq[4];
  #pragma unroll
  for (int t = 0; t < 4; ++t) gq[t] = g_s[q0 + g16 * 4 + t];

  float s4[4] = {0.f, 0.f, 0.f, 0.f};
  size_t pbase = (size_t)bh * 64 * 1024 * 16;

  for (int ch = 0; ch < 8; ++ch) {
    __syncthreads();                       // prev chunk consumers done
    #pragma unroll
    for (int t2 = 0; t2 < 2; ++t2) {
      int f2 = t2 * 256 + tid;
      int row = f2 >> 2, c4 = f2 & 3;
      uint4 vh = *(const uint4*)(Kh + bhb + (size_t)(ch * 128 + row) * HD_ + c4 * 8);
      uint4 vl = *(const uint4*)(Kl + bhb + (size_t)(ch * 128 + row) * HD_ + c4 * 8);
      int phys = row * 64 + ((c4 ^ (row & 3)) << 4);
      *(uint4*)((char*)kbufh + phys) = vh;
      *(uint4*)((char*)kbufl + phys) = vl;
    }
    __syncthreads();
    #pragma unroll
    for (int kt2 = 0; kt2 < 8; ++kt2) {
      int kt = ch * 8 + kt2;
      int kvl = kt2 * 16 + lanelo;
      int phys = kvl * 64 + ((g16 ^ (kvl & 3)) << 4);
      bf16x8 bh8 = *(const bf16x8*)((char*)kbufh + phys);
      bf16x8 bl8 = *(const bf16x8*)((char*)kbufl + phys);
      f32x4 acc = {0.f, 0.f, 0.f, 0.f};
      acc = __builtin_amdgcn_mfma_f32_16x16x32_bf16(aQh, bh8, acc, 0, 0, 0);
      acc = __builtin_amdgcn_mfma_f32_16x16x32_bf16(aQh, bl8, acc, 0, 0, 0);
      acc = __builtin_amdgcn_mfma_f32_16x16x32_bf16(aQl, bh8, acc, 0, 0, 0);
      int gcol = g_s[kt * 16 + lanelo];
      #pragma unroll
      for (int t = 0; t < 4; ++t) {
        float e = __expf(acc[t]);
        s4[t] += e;
        int r = g16 * 4 + t;
        bool keep = ((gcol == gq[t]) == samehead);
        float me = keep ? e : 0.f;
        int pc = (lanelo >> 2) ^ (r & 3) ^ (r >> 2);
        bounce[w][r * 16 + pc * 4 + (lanelo & 3)] = me;
      }
      // transpose read: lane -> (q-row r2 = l>>2, kv cols (l&3)*4..+4)
      int r2 = l >> 2;
      int pc2 = (l & 3) ^ (r2 & 3) ^ (r2 >> 2);
      float4 pv4 = *(float4*)&bounce[w][r2 * 16 + pc2 * 4];
      unsigned u0 = ((unsigned)f2bf(pv4.y) << 16) | f2bf(pv4.x);
      unsigned u1 = ((unsigned)f2bf(pv4.w) << 16) | f2bf(pv4.z);
      uint2 st = {u0, u1};
      *(uint2*)(Pp + pbase + ((size_t)kt * 1024 + q0 + r2) * 16 + (l & 3) * 4) = st;
    }
  }
  #pragma unroll
  for (int t = 0; t < 4; ++t) {
    #pragma unroll
    for (int off = 1; off < 16; off <<= 1) s4[t] += __shfl_xor(s4[t], off);
  }
  if (lanelo == 0) {
    #pragma unroll
    for (int t = 0; t < 4; ++t)
      rinv[(size_t)bh * N_ + q0 + g16 * 4 + t] = 1.0f / s4[t];
  }
}

// ---------------- colpass: colsum -> colinv -> V' (bf16 hi/lo, transposed) --
// grid (64,48) XCD-swizzled; block = one (bh, mt=16 kv cols).
__global__ __launch_bounds__(256) void colpass(const unsigned short* __restrict__ Pp,
                                               const float* __restrict__ rinv,
                                               const float* __restrict__ qkv,
                                               unsigned short* __restrict__ Vth,
                                               unsigned short* __restrict__ Vtl) {
  __shared__ float red[256][9];
  __shared__ float colinv_s[16];
  __shared__ unsigned short vh_s[32][16];
  __shared__ unsigned short vl_s[32][16];
  int tid = threadIdx.x;
  int flat = blockIdx.y * 64 + blockIdx.x;
  int nf = (flat & 7) * 384 + (flat >> 3);
  int bh = nf >> 6, mt = nf & 63;
  int b = bh / NH_, hd = bh % NH_;
  const unsigned short* pb = Pp + ((size_t)(bh * 64 + mt) * 1024) * 16;
  const float* rv = rinv + (size_t)bh * N_;
  int oct = tid & 1, nrow0 = tid >> 1;
  float s[8] = {};
  #pragma unroll
  for (int p = 0; p < 8; ++p) {
    int n = p * 128 + nrow0;
    uint4 v = *(const uint4*)(pb + (size_t)n * 16 + oct * 8);
    float rn = rv[n];
    s[0] += bf2f((unsigned short)(v.x & 0xffff)) * rn;
    s[1] += bf2f((unsigned short)(v.x >> 16)) * rn;
    s[2] += bf2f((unsigned short)(v.y & 0xffff)) * rn;
    s[3] += bf2f((unsigned short)(v.y >> 16)) * rn;
    s[4] += bf2f((unsigned short)(v.z & 0xffff)) * rn;
    s[5] += bf2f((unsigned short)(v.z >> 16)) * rn;
    s[6] += bf2f((unsigned short)(v.w & 0xffff)) * rn;
    s[7] += bf2f((unsigned short)(v.w >> 16)) * rn;
  }
  int ridx = oct * 128 + nrow0;
  #pragma unroll
  for (int j = 0; j < 8; ++j) red[ridx][j] = s[j];
  __syncthreads();
  for (int st = 64; st > 0; st >>= 1) {
    if (nrow0 < st) {
      #pragma unroll
      for (int j = 0; j < 8; ++j) red[ridx][j] += red[ridx + st][j];
    }
    __syncthreads();
  }
  if (tid < 16)
    colinv_s[tid] = 1.0f / (red[(tid >> 3) * 128][tid & 7] + 1e-8f);
  __syncthreads();
  if (tid < 128) {
    int m = tid >> 3, d4 = (tid & 7) * 4;
    float4 v = *(const float4*)(qkv + ((size_t)(b * N_ + mt * 16 + m)) * H3_ +
                                2 * C_ + hd * HD_ + d4);
    float ci = colinv_s[m];
    float va[4] = {v.x * ci, v.y * ci, v.z * ci, v.w * ci};
    #pragma unroll
    for (int i = 0; i < 4; ++i) {
      unsigned short h = f2bf(va[i]);
      vh_s[d4 + i][m] = h;
      vl_s[d4 + i][m] = f2bf(va[i] - bf2f(h));
    }
  }
  __syncthreads();
  if (tid < 64) {
    int d = tid >> 1, m8 = (tid & 1) * 8;
    uint4 h = *(uint4*)&vh_s[d][m8];
    *(uint4*)(Vth + ((size_t)bh * HD_ + d) * N_ + mt * 16 + m8) = h;
  } else if (tid < 128) {
    int t2 = tid - 64;
    int d = t2 >> 1, m8 = (t2 & 1) * 8;
    uint4 lo = *(uint4*)&vl_s[d][m8];
    *(uint4*)(Vtl + ((size_t)bh * HD_ + d) * N_ + mt * 16 + m8) = lo;
  }
}

// ---------------- pv: O = P' @ V' (MFMA), epilogue * rinv -------------------
// grid (8,48) XCD-swizzled; 4 waves, wave = 32 q-rows (2 ntiles) x 32 d.
__global__ __launch_bounds__(256) void pv(const unsigned short* __restrict__ Pp,
                                          const unsigned short* __restrict__ Vth,
                                          const unsigned short* __restrict__ Vtl,
                                          const float* __restrict__ rinv,
                                          float* __restrict__ attnout) {
  int tid = threadIdx.x;
  int l = tid & 63, w = tid >> 6;
  int lanelo = l & 15, g16 = l >> 4;
  int flat = blockIdx.y * 8 + blockIdx.x;
  int nf = (flat & 7) * 48 + (flat >> 3);
  int bh = nf >> 3, nt = nf & 7;
  int b = bh / NH_, hd = bh % NH_;
  int n0 = nt * 128 + w * 32;
  size_t pB = (size_t)bh * 64 * 1024 * 16;
  const unsigned short* vh = Vth + (size_t)bh * HD_ * N_;
  const unsigned short* vl = Vtl + (size_t)bh * HD_ * N_;
  f32x4 o00 = {0.f,0.f,0.f,0.f}, o01 = {0.f,0.f,0.f,0.f};
  f32x4 o10 = {0.f,0.f,0.f,0.f}, o11 = {0.f,0.f,0.f,0.f};
  for (int kc = 0; kc < 32; ++kc) {
    int mt = kc * 2 + (g16 >> 1);
    int mi = (g16 & 1) * 8;
    bf16x8 a0 = *(const bf16x8*)(Pp + pB + ((size_t)mt * 1024 + n0 + lanelo) * 16 + mi);
    bf16x8 a1 = *(const bf16x8*)(Pp + pB + ((size_t)mt * 1024 + n0 + 16 + lanelo) * 16 + mi);
    size_t vo0 = (size_t)lanelo * N_ + kc * 32 + g16 * 8;
    size_t vo1 = (size_t)(16 + lanelo) * N_ + kc * 32 + g16 * 8;
    bf16x8 b0h = *(const bf16x8*)(vh + vo0);
    bf16x8 b0l = *(const bf16x8*)(vl + vo0);
    bf16x8 b1h = *(const bf16x8*)(vh + vo1);
    bf16x8 b1l = *(const bf16x8*)(vl + vo1);
    o00 = __builtin_amdgcn_mfma_f32_16x16x32_bf16(a0, b0h, o00, 0, 0, 0);
    o00 = __builtin_amdgcn_mfma_f32_16x16x32_bf16(a0, b0l, o00, 0, 0, 0);
    o01 = __builtin_amdgcn_mfma_f32_16x16x32_bf16(a0, b1h, o01, 0, 0, 0);
    o01 = __builtin_amdgcn_mfma_f32_16x16x32_bf16(a0, b1l, o01, 0, 0, 0);
    o10 = __builtin_amdgcn_mfma_f32_16x16x32_bf16(a1, b0h, o10, 0, 0, 0);
    o10 = __builtin_amdgcn_mfma_f32_16x16x32_bf16(a1, b0l, o10, 0, 0, 0);
    o11 = __builtin_amdgcn_mfma_f32_16x16x32_bf16(a1, b1h, o11, 0, 0, 0);
    o11 = __builtin_amdgcn_mfma_f32_16x16x32_bf16(a1, b1l, o11, 0, 0, 0);
  }
  float4 rv0 = *(const float4*)(rinv + (size_t)bh * N_ + n0 + g16 * 4);
  float4 rv1 = *(const float4*)(rinv + (size_t)bh * N_ + n0 + 16 + g16 * 4);
  float r0a[4] = {rv0.x, rv0.y, rv0.z, rv0.w};
  float r1a[4] = {rv1.x, rv1.y, rv1.z, rv1.w};
  #pragma unroll
  for (int t = 0; t < 4; ++t) {
    size_t row0 = (size_t)(b * N_ + n0 + g16 * 4 + t) * C_ + hd * HD_;
    size_t row1 = (size_t)(b * N_ + n0 + 16 + g16 * 4 + t) * C_ + hd * HD_;
    attnout[row0 + lanelo]      = o00[t] * r0a[t];
    attnout[row0 + 16 + lanelo] = o01[t] * r0a[t];
    attnout[row1 + lanelo]      = o10[t] * r1a[t];
    attnout[row1 + 16 + lanelo] = o11[t] * r1a[t];
  }
}

// ---------------- launch ----------------------------------------------------
extern "C" void kernel_launch(void* const* d_in, const int* in_sizes, int n_in,
                              void* d_out, int out_size, void* d_ws, size_t ws_size,
                              hipStream_t stream) {
  const float* x     = (const float*)d_in[0];
  const float* Wqkv  = (const float*)d_in[1];
  const float* Wproj = (const float*)d_in[2];
  const float* Wgp   = (const float*)d_in[3];
  float* out = (float*)d_out;
  float* ws  = (float*)d_ws;

  float* qkv     = ws;                          // 4,718,592 f
  float* attnout = ws + 4718592;                // 1,572,864 f
  float* rinv    = ws + 6291456;                //    49,152 f
  int*   group   = (int*)(ws + 6340608);        //     4,096 i
  double* Mgp    = (double*)(ws + 6344704);     //     7,680 d (8B-aligned)
  unsigned short* bfb = (unsigned short*)(ws + 6360064);
  const size_t BSZ = (size_t)BH_ * N_ * HD_;    // 1,572,864 ushorts each
  unsigned short* Qh  = bfb;
  unsigned short* Ql  = bfb + BSZ;
  unsigned short* Kh  = bfb + 2 * BSZ;
  unsigned short* Kl  = bfb + 3 * BSZ;
  unsigned short* Vth = bfb + 4 * BSZ;
  unsigned short* Vtl = bfb + 5 * BSZ;
  unsigned short* Pp  = (unsigned short*)(ws + 11078656);  // 50,331,648 us (96MB)

  gemm_nt<<<dim3(18, 64), 256, 0, stream>>>(x, Wqkv, qkv, 4096, H3_, C_);
  wgp_fuse<<<dim3(30), 256, 0, stream>>>(Wqkv, Wgp, Mgp);
  group_assign2<<<dim3(256), 320, 0, stream>>>(x, Mgp, group);
  prep2<<<dim3(32, BH_), 256, 0, stream>>>(qkv, Qh, Ql, Kh, Kl);
  score<<<dim3(16, BH_), 256, 0, stream>>>(Qh, Ql, Kh, Kl, group, rinv, Pp);
  colpass<<<dim3(64, BH_), 256, 0, stream>>>(Pp, rinv, qkv, Vth, Vtl);
  pv<<<dim3(8, BH_), 256, 0, stream>>>(Pp, Vth, Vtl, rinv, attnout);
  gemm_nt<<<dim3(6, 64), 256, 0, stream>>>(attnout, Wproj, out, 4096, C_, C_);
}

// Round 6
// 191.784 us; speedup vs baseline: 1.9811x; 1.1845x over previous
//
#include <hip/hip_runtime.h>
#include <hip/hip_bf16.h>

// HardgroupAttention: B=4, N=1024, C=384, heads=12, hd=32, GP=20.
// conv3 (x,Wqkv,Wproj -> bf16 hi/lo) -> wgp_fuse + group argmax (fp64, exact)
// -> gemm_mfma<1> (qkv via 3-term bf16-split MFMA; epilogue emits Qh/Ql
// scaled, Kh/Kl, Vf fp32) -> score (1 MFMA QK^T sweep, no-max softmax, mask
// -> P' bf16 + rinv) -> colpass (colsum -> V' = V*colinv bf16 hi/lo, transp)
// -> pv (O = P' @ V' MFMA; epilogue bf16 hi/lo) -> gemm_mfma<0> (proj -> out).

#define B_    4
#define N_    1024
#define C_    384
#define H3_   1152
#define NH_   12
#define HD_   32
#define GP_   20
#define BH_   48
#define SCALE 0.17677669529663687f

typedef __attribute__((ext_vector_type(8))) short bf16x8;
typedef __attribute__((ext_vector_type(4))) float f32x4;

static __device__ __forceinline__ unsigned short f2bf(float x) {
  union { float f; unsigned u; } v; v.f = x;
  unsigned r = v.u + 0x7fff + ((v.u >> 16) & 1);   // RNE
  return (unsigned short)(r >> 16);
}
static __device__ __forceinline__ float bf2f(unsigned short h) {
  union { unsigned u; float f; } v; v.u = ((unsigned)h) << 16;
  return v.f;
}

// ---------------- conv3: split x / Wqkv / Wproj into bf16 hi/lo -------------
__global__ __launch_bounds__(256) void conv3(const float* __restrict__ x,
                                             const float* __restrict__ wq,
                                             const float* __restrict__ wp,
                                             unsigned short* __restrict__ xh,
                                             unsigned short* __restrict__ xl,
                                             unsigned short* __restrict__ wqh,
                                             unsigned short* __restrict__ wql,
                                             unsigned short* __restrict__ wph,
                                             unsigned short* __restrict__ wpl) {
  const int NX = (4096 * C_) / 4, NQ = (H3_ * C_) / 4, NP = (C_ * C_) / 4;
  int idx = blockIdx.x * 256 + threadIdx.x;
  const float* src; unsigned short *dh, *dl; int o;
  if (idx < NX)            { src = x;  dh = xh;  dl = xl;  o = idx; }
  else if (idx < NX + NQ)  { src = wq; dh = wqh; dl = wql; o = idx - NX; }
  else if (idx < NX + NQ + NP) { src = wp; dh = wph; dl = wpl; o = idx - NX - NQ; }
  else return;
  float4 v = *(const float4*)(src + (size_t)o * 4);
  float a[4] = {v.x, v.y, v.z, v.w};
  unsigned short h[4], lo[4];
  #pragma unroll
  for (int i = 0; i < 4; ++i) { h[i] = f2bf(a[i]); lo[i] = f2bf(a[i] - bf2f(h[i])); }
  uint2 ph = {(unsigned)h[0]  | ((unsigned)h[1]  << 16),
              (unsigned)h[2]  | ((unsigned)h[3]  << 16)};
  uint2 pl = {(unsigned)lo[0] | ((unsigned)lo[1] << 16),
              (unsigned)lo[2] | ((unsigned)lo[3] << 16)};
  *(uint2*)(dh + (size_t)o * 4) = ph;
  *(uint2*)(dl + (size_t)o * 4) = pl;
}

// ---------------- M[g][c] = sum_j Wgp[g][j] * Wqkv[j][c]  (fp64) ------------
__global__ __launch_bounds__(256) void wgp_fuse(const float* __restrict__ Wqkv,
                                                const float* __restrict__ Wgp,
                                                double* __restrict__ M) {
  int idx = blockIdx.x * 256 + threadIdx.x;
  if (idx >= GP_ * C_) return;
  int g = idx / C_, c = idx % C_;
  double acc = 0.0;
  for (int j = 0; j < C_; ++j)
    acc += (double)Wgp[g * C_ + j] * (double)Wqkv[(size_t)j * C_ + c];
  M[idx] = acc;
}

// ---------------- group argmax from exact x (fp64) --------------------------
__global__ __launch_bounds__(320) void group_assign2(const float* __restrict__ x,
                                                     const double* __restrict__ M,
                                                     int* __restrict__ group) {
  __shared__ double sc[16][GP_];
  int tid = threadIdx.x;
  int r = tid / GP_, g = tid % GP_;
  int n = blockIdx.x * 16 + r;
  const float* row = x + (size_t)n * C_;
  const double* w = M + (size_t)g * C_;
  double acc = 0.0;
  for (int c = 0; c < C_; ++c) acc += (double)row[c] * w[c];
  sc[r][g] = acc;
  __syncthreads();
  if (g == 0) {
    int best = 0; double bv = sc[r][0];
    #pragma unroll
    for (int j = 1; j < GP_; ++j)
      if (sc[r][j] > bv) { bv = sc[r][j]; best = j; }
    group[n] = best;
  }
}

// ---------------- gemm_mfma: C = A @ B^T via 3-term bf16-split MFMA ---------
// 128x128 tile, BK=32, 4 waves (2x2 quadrants of 64x64 = 4x4 16x16 frags).
// LDS rows padded to 40 ushorts (80B) -> 2-way bank aliasing (free).
// MODE 0: write Cm fp32 [M][Nn]. MODE 1 (qkv, Nn=1152): col-tile regions are
// block-uniform: bn 0-2 -> Qh/Ql (scaled), 3-5 -> Kh/Kl, 6-8 -> Vf fp32.
template<int MODE>
__global__ __launch_bounds__(256) void gemm_mfma(
    const unsigned short* __restrict__ Ah_g, const unsigned short* __restrict__ Al_g,
    const unsigned short* __restrict__ Bh_g, const unsigned short* __restrict__ Bl_g,
    float* __restrict__ Cm, int Nn,
    unsigned short* __restrict__ Qh, unsigned short* __restrict__ Ql,
    unsigned short* __restrict__ Kh, unsigned short* __restrict__ Kl,
    float* __restrict__ Vf) {
  __shared__ __align__(16) unsigned short sAh[128 * 40];
  __shared__ __align__(16) unsigned short sAl[128 * 40];
  __shared__ __align__(16) unsigned short sBh[128 * 40];
  __shared__ __align__(16) unsigned short sBl[128 * 40];
  int tid = threadIdx.x;
  int l = tid & 63, w = tid >> 6;
  int lanelo = l & 15, g16 = l >> 4;
  int wr = w >> 1, wc = w & 1;
  int bn = blockIdx.x, bm = blockIdx.y;

  const unsigned short* sg;
  unsigned short* sd;
  int rb;
  if (w == 0)      { sg = Ah_g; sd = sAh; rb = bm; }
  else if (w == 1) { sg = Al_g; sd = sAl; rb = bm; }
  else if (w == 2) { sg = Bh_g; sd = sBh; rb = bn; }
  else             { sg = Bl_g; sd = sBl; rb = bn; }
  const unsigned short* gsrc = sg + (size_t)(rb * 128 + (l >> 2)) * C_ + (l & 3) * 8;
  unsigned short* ldst = sd + (l >> 2) * 40 + (l & 3) * 8;

  f32x4 acc[4][4];
  #pragma unroll
  for (int i = 0; i < 4; ++i)
    #pragma unroll
    for (int j = 0; j < 4; ++j) acc[i][j] = (f32x4){0.f, 0.f, 0.f, 0.f};

  for (int kk = 0; kk < C_; kk += 32) {
    __syncthreads();
    #pragma unroll
    for (int i = 0; i < 8; ++i) {
      uint4 v = *(const uint4*)(gsrc + (size_t)(i * 16) * C_ + kk);
      *(uint4*)(ldst + i * 16 * 40) = v;
    }
    __syncthreads();
    bf16x8 ah[4], al[4], bh8[4], bl8[4];
    #pragma unroll
    for (int i = 0; i < 4; ++i) {
      int r = (wr * 64 + i * 16 + lanelo) * 40 + g16 * 8;
      ah[i] = *(const bf16x8*)(sAh + r);
      al[i] = *(const bf16x8*)(sAl + r);
    }
    #pragma unroll
    for (int j = 0; j < 4; ++j) {
      int r = (wc * 64 + j * 16 + lanelo) * 40 + g16 * 8;
      bh8[j] = *(const bf16x8*)(sBh + r);
      bl8[j] = *(const bf16x8*)(sBl + r);
    }
    #pragma unroll
    for (int i = 0; i < 4; ++i)
      #pragma unroll
      for (int j = 0; j < 4; ++j) {
        acc[i][j] = __builtin_amdgcn_mfma_f32_16x16x32_bf16(ah[i], bh8[j], acc[i][j], 0, 0, 0);
        acc[i][j] = __builtin_amdgcn_mfma_f32_16x16x32_bf16(ah[i], bl8[j], acc[i][j], 0, 0, 0);
        acc[i][j] = __builtin_amdgcn_mfma_f32_16x16x32_bf16(al[i], bh8[j], acc[i][j], 0, 0, 0);
      }
  }

  if (MODE == 0) {
    #pragma unroll
    for (int i = 0; i < 4; ++i) {
      int mm = bm * 128 + wr * 64 + i * 16 + g16 * 4;
      #pragma unroll
      for (int j = 0; j < 4; ++j) {
        int c = bn * 128 + wc * 64 + j * 16 + lanelo;
        #pragma unroll
        for (int t = 0; t < 4; ++t)
          Cm[(size_t)(mm + t) * Nn + c] = acc[i][j][t];
      }
    }
  } else {
    int region = bn / 3;   // 0=Q 1=K 2=V (block-uniform)
    #pragma unroll
    for (int i = 0; i < 4; ++i) {
      int mm0 = bm * 128 + wr * 64 + i * 16 + g16 * 4;
      #pragma unroll
      for (int j = 0; j < 4; ++j) {
        int c = bn * 128 + wc * 64 + j * 16 + lanelo;
        int cc = c - region * 384;   // 0..383
        #pragma unroll
        for (int t = 0; t < 4; ++t) {
          int mm = mm0 + t;
          int b = mm >> 10, n = mm & 1023;
          float v = acc[i][j][t];
          if (region == 0) {
            v *= SCALE;
            unsigned short h = f2bf(v), lo = f2bf(v - bf2f(h));
            size_t idx = ((size_t)(b * NH_ + (cc >> 5)) * N_ + n) * HD_ + (cc & 31);
            Qh[idx] = h; Ql[idx] = lo;
          } else if (region == 1) {
            unsigned short h = f2bf(v), lo = f2bf(v - bf2f(h));
            size_t idx = ((size_t)(b * NH_ + (cc >> 5)) * N_ + n) * HD_ + (cc & 31);
            Kh[idx] = h; Kl[idx] = lo;
          } else {
            Vf[(size_t)mm * C_ + cc] = v;
          }
        }
      }
    }
  }
}

// ---------------- score: single QK^T sweep -> P' bf16 + rinv ----------------
__global__ __launch_bounds__(256) void score(const unsigned short* __restrict__ Qh,
                                             const unsigned short* __restrict__ Ql,
                                             const unsigned short* __restrict__ Kh,
                                             const unsigned short* __restrict__ Kl,
                                             const int* __restrict__ group,
                                             float* __restrict__ rinv,
                                             unsigned short* __restrict__ Pp) {
  __shared__ __align__(16) unsigned short kbufh[4096];
  __shared__ __align__(16) unsigned short kbufl[4096];
  __shared__ __align__(16) float bounce[4][256];
  __shared__ int g_s[1024];
  int tid = threadIdx.x;
  int l = tid & 63, w = tid >> 6;
  int lanelo = l & 15, g16 = l >> 4;
  int flat = blockIdx.y * 16 + blockIdx.x;
  int nf = (flat & 7) * 96 + (flat >> 3);
  int bh = nf >> 4, blk = nf & 15;
  int b = bh / NH_;
  bool samehead = ((bh % NH_) < NH_ / 2);
  int q0 = blk * 64 + w * 16;
  size_t bhb = (size_t)bh * (N_ * HD_);

  *(int4*)&g_s[tid * 4] = *(const int4*)(group + b * N_ + tid * 4);
  bf16x8 aQh = *(const bf16x8*)(Qh + bhb + (size_t)(q0 + lanelo) * HD_ + g16 * 8);
  bf16x8 aQl = *(const bf16x8*)(Ql + bhb + (size_t)(q0 + lanelo) * HD_ + g16 * 8);
  __syncthreads();
  int gq[4];
  #pragma unroll
  for (int t = 0; t < 4; ++t) gq[t] = g_s[q0 + g16 * 4 + t];

  float s4[4] = {0.f, 0.f, 0.f, 0.f};
  size_t pbase = (size_t)bh * 64 * 1024 * 16;

  for (int ch = 0; ch < 8; ++ch) {
    __syncthreads();
    #pragma unroll
    for (int t2 = 0; t2 < 2; ++t2) {
      int f2 = t2 * 256 + tid;
      int row = f2 >> 2, c4 = f2 & 3;
      uint4 vh = *(const uint4*)(Kh + bhb + (size_t)(ch * 128 + row) * HD_ + c4 * 8);
      uint4 vl = *(const uint4*)(Kl + bhb + (size_t)(ch * 128 + row) * HD_ + c4 * 8);
      int phys = row * 64 + ((c4 ^ (row & 3)) << 4);
      *(uint4*)((char*)kbufh + phys) = vh;
      *(uint4*)((char*)kbufl + phys) = vl;
    }
    __syncthreads();
    #pragma unroll
    for (int kt2 = 0; kt2 < 8; ++kt2) {
      int kt = ch * 8 + kt2;
      int kvl = kt2 * 16 + lanelo;
      int phys = kvl * 64 + ((g16 ^ (kvl & 3)) << 4);
      bf16x8 bh8 = *(const bf16x8*)((char*)kbufh + phys);
      bf16x8 bl8 = *(const bf16x8*)((char*)kbufl + phys);
      f32x4 acc = {0.f, 0.f, 0.f, 0.f};
      acc = __builtin_amdgcn_mfma_f32_16x16x32_bf16(aQh, bh8, acc, 0, 0, 0);
      acc = __builtin_amdgcn_mfma_f32_16x16x32_bf16(aQh, bl8, acc, 0, 0, 0);
      acc = __builtin_amdgcn_mfma_f32_16x16x32_bf16(aQl, bh8, acc, 0, 0, 0);
      int gcol = g_s[kt * 16 + lanelo];
      #pragma unroll
      for (int t = 0; t < 4; ++t) {
        float e = __expf(acc[t]);
        s4[t] += e;
        int r = g16 * 4 + t;
        bool keep = ((gcol == gq[t]) == samehead);
        float me = keep ? e : 0.f;
        int pc = (lanelo >> 2) ^ (r & 3) ^ (r >> 2);
        bounce[w][r * 16 + pc * 4 + (lanelo & 3)] = me;
      }
      int r2 = l >> 2;
      int pc2 = (l & 3) ^ (r2 & 3) ^ (r2 >> 2);
      float4 pv4 = *(float4*)&bounce[w][r2 * 16 + pc2 * 4];
      unsigned u0 = ((unsigned)f2bf(pv4.y) << 16) | f2bf(pv4.x);
      unsigned u1 = ((unsigned)f2bf(pv4.w) << 16) | f2bf(pv4.z);
      uint2 st = {u0, u1};
      *(uint2*)(Pp + pbase + ((size_t)kt * 1024 + q0 + r2) * 16 + (l & 3) * 4) = st;
    }
  }
  #pragma unroll
  for (int t = 0; t < 4; ++t) {
    #pragma unroll
    for (int off = 1; off < 16; off <<= 1) s4[t] += __shfl_xor(s4[t], off);
  }
  if (lanelo == 0) {
    #pragma unroll
    for (int t = 0; t < 4; ++t)
      rinv[(size_t)bh * N_ + q0 + g16 * 4 + t] = 1.0f / s4[t];
  }
}

// ---------------- colpass: colsum -> colinv -> V' (bf16 hi/lo, transposed) --
__global__ __launch_bounds__(256) void colpass(const unsigned short* __restrict__ Pp,
                                               const float* __restrict__ rinv,
                                               const float* __restrict__ Vf,
                                               unsigned short* __restrict__ Vth,
                                               unsigned short* __restrict__ Vtl) {
  __shared__ float red[256][9];
  __shared__ float colinv_s[16];
  __shared__ unsigned short vh_s[32][16];
  __shared__ unsigned short vl_s[32][16];
  int tid = threadIdx.x;
  int flat = blockIdx.y * 64 + blockIdx.x;
  int nf = (flat & 7) * 384 + (flat >> 3);
  int bh = nf >> 6, mt = nf & 63;
  int b = bh / NH_, hd = bh % NH_;
  const unsigned short* pb = Pp + ((size_t)(bh * 64 + mt) * 1024) * 16;
  const float* rv = rinv + (size_t)bh * N_;
  int oct = tid & 1, nrow0 = tid >> 1;
  float s[8] = {};
  #pragma unroll
  for (int p = 0; p < 8; ++p) {
    int n = p * 128 + nrow0;
    uint4 v = *(const uint4*)(pb + (size_t)n * 16 + oct * 8);
    float rn = rv[n];
    s[0] += bf2f((unsigned short)(v.x & 0xffff)) * rn;
    s[1] += bf2f((unsigned short)(v.x >> 16)) * rn;
    s[2] += bf2f((unsigned short)(v.y & 0xffff)) * rn;
    s[3] += bf2f((unsigned short)(v.y >> 16)) * rn;
    s[4] += bf2f((unsigned short)(v.z & 0xffff)) * rn;
    s[5] += bf2f((unsigned short)(v.z >> 16)) * rn;
    s[6] += bf2f((unsigned short)(v.w & 0xffff)) * rn;
    s[7] += bf2f((unsigned short)(v.w >> 16)) * rn;
  }
  int ridx = oct * 128 + nrow0;
  #pragma unroll
  for (int j = 0; j < 8; ++j) red[ridx][j] = s[j];
  __syncthreads();
  for (int st = 64; st > 0; st >>= 1) {
    if (nrow0 < st) {
      #pragma unroll
      for (int j = 0; j < 8; ++j) red[ridx][j] += red[ridx + st][j];
    }
    __syncthreads();
  }
  if (tid < 16)
    colinv_s[tid] = 1.0f / (red[(tid >> 3) * 128][tid & 7] + 1e-8f);
  __syncthreads();
  if (tid < 128) {
    int m = tid >> 3, d4 = (tid & 7) * 4;
    float4 v = *(const float4*)(Vf + ((size_t)(b * N_ + mt * 16 + m)) * C_ +
                                hd * HD_ + d4);
    float ci = colinv_s[m];
    float va[4] = {v.x * ci, v.y * ci, v.z * ci, v.w * ci};
    #pragma unroll
    for (int i = 0; i < 4; ++i) {
      unsigned short h = f2bf(va[i]);
      vh_s[d4 + i][m] = h;
      vl_s[d4 + i][m] = f2bf(va[i] - bf2f(h));
    }
  }
  __syncthreads();
  if (tid < 64) {
    int d = tid >> 1, m8 = (tid & 1) * 8;
    uint4 h = *(uint4*)&vh_s[d][m8];
    *(uint4*)(Vth + ((size_t)bh * HD_ + d) * N_ + mt * 16 + m8) = h;
  } else if (tid < 128) {
    int t2 = tid - 64;
    int d = t2 >> 1, m8 = (t2 & 1) * 8;
    uint4 lo = *(uint4*)&vl_s[d][m8];
    *(uint4*)(Vtl + ((size_t)bh * HD_ + d) * N_ + mt * 16 + m8) = lo;
  }
}

// ---------------- pv: O = P' @ V' (MFMA), epilogue *rinv -> bf16 hi/lo ------
__global__ __launch_bounds__(256) void pv(const unsigned short* __restrict__ Pp,
                                          const unsigned short* __restrict__ Vth,
                                          const unsigned short* __restrict__ Vtl,
                                          const float* __restrict__ rinv,
                                          unsigned short* __restrict__ aoh,
                                          unsigned short* __restrict__ aol) {
  int tid = threadIdx.x;
  int l = tid & 63, w = tid >> 6;
  int lanelo = l & 15, g16 = l >> 4;
  int flat = blockIdx.y * 8 + blockIdx.x;
  int nf = (flat & 7) * 48 + (flat >> 3);
  int bh = nf >> 3, nt = nf & 7;
  int b = bh / NH_, hd = bh % NH_;
  int n0 = nt * 128 + w * 32;
  size_t pB = (size_t)bh * 64 * 1024 * 16;
  const unsigned short* vh = Vth + (size_t)bh * HD_ * N_;
  const unsigned short* vl = Vtl + (size_t)bh * HD_ * N_;
  f32x4 o00 = {0.f,0.f,0.f,0.f}, o01 = {0.f,0.f,0.f,0.f};
  f32x4 o10 = {0.f,0.f,0.f,0.f}, o11 = {0.f,0.f,0.f,0.f};
  for (int kc = 0; kc < 32; ++kc) {
    int mt = kc * 2 + (g16 >> 1);
    int mi = (g16 & 1) * 8;
    bf16x8 a0 = *(const bf16x8*)(Pp + pB + ((size_t)mt * 1024 + n0 + lanelo) * 16 + mi);
    bf16x8 a1 = *(const bf16x8*)(Pp + pB + ((size_t)mt * 1024 + n0 + 16 + lanelo) * 16 + mi);
    size_t vo0 = (size_t)lanelo * N_ + kc * 32 + g16 * 8;
    size_t vo1 = (size_t)(16 + lanelo) * N_ + kc * 32 + g16 * 8;
    bf16x8 b0h = *(const bf16x8*)(vh + vo0);
    bf16x8 b0l = *(const bf16x8*)(vl + vo0);
    bf16x8 b1h = *(const bf16x8*)(vh + vo1);
    bf16x8 b1l = *(const bf16x8*)(vl + vo1);
    o00 = __builtin_amdgcn_mfma_f32_16x16x32_bf16(a0, b0h, o00, 0, 0, 0);
    o00 = __builtin_amdgcn_mfma_f32_16x16x32_bf16(a0, b0l, o00, 0, 0, 0);
    o01 = __builtin_amdgcn_mfma_f32_16x16x32_bf16(a0, b1h, o01, 0, 0, 0);
    o01 = __builtin_amdgcn_mfma_f32_16x16x32_bf16(a0, b1l, o01, 0, 0, 0);
    o10 = __builtin_amdgcn_mfma_f32_16x16x32_bf16(a1, b0h, o10, 0, 0, 0);
    o10 = __builtin_amdgcn_mfma_f32_16x16x32_bf16(a1, b0l, o10, 0, 0, 0);
    o11 = __builtin_amdgcn_mfma_f32_16x16x32_bf16(a1, b1h, o11, 0, 0, 0);
    o11 = __builtin_amdgcn_mfma_f32_16x16x32_bf16(a1, b1l, o11, 0, 0, 0);
  }
  float4 rv0 = *(const float4*)(rinv + (size_t)bh * N_ + n0 + g16 * 4);
  float4 rv1 = *(const float4*)(rinv + (size_t)bh * N_ + n0 + 16 + g16 * 4);
  float r0a[4] = {rv0.x, rv0.y, rv0.z, rv0.w};
  float r1a[4] = {rv1.x, rv1.y, rv1.z, rv1.w};
  #pragma unroll
  for (int t = 0; t < 4; ++t) {
    size_t row0 = (size_t)(b * N_ + n0 + g16 * 4 + t) * C_ + hd * HD_;
    size_t row1 = (size_t)(b * N_ + n0 + 16 + g16 * 4 + t) * C_ + hd * HD_;
    float v00 = o00[t] * r0a[t], v01 = o01[t] * r0a[t];
    float v10 = o10[t] * r1a[t], v11 = o11[t] * r1a[t];
    unsigned short h;
    h = f2bf(v00); aoh[row0 + lanelo]      = h; aol[row0 + lanelo]      = f2bf(v00 - bf2f(h));
    h = f2bf(v01); aoh[row0 + 16 + lanelo] = h; aol[row0 + 16 + lanelo] = f2bf(v01 - bf2f(h));
    h = f2bf(v10); aoh[row1 + lanelo]      = h; aol[row1 + lanelo]      = f2bf(v10 - bf2f(h));
    h = f2bf(v11); aoh[row1 + 16 + lanelo] = h; aol[row1 + 16 + lanelo] = f2bf(v11 - bf2f(h));
  }
}

// ---------------- launch ----------------------------------------------------
extern "C" void kernel_launch(void* const* d_in, const int* in_sizes, int n_in,
                              void* d_out, int out_size, void* d_ws, size_t ws_size,
                              hipStream_t stream) {
  const float* x     = (const float*)d_in[0];
  const float* Wqkv  = (const float*)d_in[1];
  const float* Wproj = (const float*)d_in[2];
  const float* Wgp   = (const float*)d_in[3];
  float* out = (float*)d_out;

  char* base = (char*)d_ws;
  size_t off = 0;
  auto alloc = [&](size_t bytes) {
    void* p = base + off;
    off += (bytes + 255) & ~(size_t)255;
    return p;
  };
  float*  Vf    = (float*)alloc(4096ull * C_ * 4);         // 6.29 MB
  float*  rinv  = (float*)alloc((size_t)BH_ * N_ * 4);
  double* Mgp   = (double*)alloc((size_t)GP_ * C_ * 8);
  int*    group = (int*)alloc(4096ull * 4);
  unsigned short* xh  = (unsigned short*)alloc(4096ull * C_ * 2);
  unsigned short* xl  = (unsigned short*)alloc(4096ull * C_ * 2);
  unsigned short* Wqh = (unsigned short*)alloc((size_t)H3_ * C_ * 2);
  unsigned short* Wql = (unsigned short*)alloc((size_t)H3_ * C_ * 2);
  unsigned short* Wph = (unsigned short*)alloc((size_t)C_ * C_ * 2);
  unsigned short* Wpl = (unsigned short*)alloc((size_t)C_ * C_ * 2);
  unsigned short* aoh = (unsigned short*)alloc(4096ull * C_ * 2);
  unsigned short* aol = (unsigned short*)alloc(4096ull * C_ * 2);
  const size_t BSZ = (size_t)BH_ * N_ * HD_;
  unsigned short* Qh  = (unsigned short*)alloc(BSZ * 2);
  unsigned short* Ql  = (unsigned short*)alloc(BSZ * 2);
  unsigned short* Kh  = (unsigned short*)alloc(BSZ * 2);
  unsigned short* Kl  = (unsigned short*)alloc(BSZ * 2);
  unsigned short* Vth = (unsigned short*)alloc(BSZ * 2);
  unsigned short* Vtl = (unsigned short*)alloc(BSZ * 2);
  unsigned short* Pp  = (unsigned short*)alloc((size_t)BH_ * N_ * N_ * 2);  // 96 MB

  conv3<<<dim3(2112), 256, 0, stream>>>(x, Wqkv, Wproj, xh, xl, Wqh, Wql, Wph, Wpl);
  wgp_fuse<<<dim3(30), 256, 0, stream>>>(Wqkv, Wgp, Mgp);
  group_assign2<<<dim3(256), 320, 0, stream>>>(x, Mgp, group);
  gemm_mfma<1><<<dim3(9, 32), 256, 0, stream>>>(xh, xl, Wqh, Wql, nullptr, H3_,
                                                Qh, Ql, Kh, Kl, Vf);
  score<<<dim3(16, BH_), 256, 0, stream>>>(Qh, Ql, Kh, Kl, group, rinv, Pp);
  colpass<<<dim3(64, BH_), 256, 0, stream>>>(Pp, rinv, Vf, Vth, Vtl);
  pv<<<dim3(8, BH_), 256, 0, stream>>>(Pp, Vth, Vtl, rinv, aoh, aol);
  gemm_mfma<0><<<dim3(3, 32), 256, 0, stream>>>(aoh, aol, Wph, Wpl, out, C_,
                                                nullptr, nullptr, nullptr, nullptr, nullptr);
}